// Round 3
// baseline (254.499 us; speedup 1.0000x reference)
//
#include <hip/hip_runtime.h>
#include <hip/hip_bf16.h>
#include <float.h>

// Problem constants
constexpr int B  = 64;
constexpr int C  = 256;
constexpr int HW = 1024;   // 32*32
constexpr int K  = 1024;
constexpr float BETA = 0.25f;
constexpr float NTOT_INV = 1.0f / 16777216.0f;  // 1 / (64*256*32*32)

typedef __attribute__((ext_vector_type(8))) short bf16x8;
typedef __attribute__((ext_vector_type(4))) float floatx4;

union U16 { uint4 u; bf16x8 b; };

__device__ inline unsigned short f2bf(float x) {
    unsigned u = __float_as_uint(x);
    return (unsigned short)((u + 0x7FFFu + ((u >> 16) & 1u)) >> 16);  // RNE
}

// --- kernel 1: emb fp32 -> bf16 TILED [ks=ch/32][code][ch%32] + esq1 ---
// The tiling makes the vq_dist A-fragment load (lanes = (q,l15)) read a
// contiguous 1KB segment instead of 16 scattered 64B lines (R2 bottleneck).
// grid 256 x 256 threads.
__global__ __launch_bounds__(256) void prep_kernel(const float* __restrict__ emb,
                                                   short* __restrict__ ebf2,
                                                   float* __restrict__ esq1,
                                                   float* __restrict__ acc_loss) {
    if (blockIdx.x == 0 && threadIdx.x < 2) acc_loss[threadIdx.x] = 0.0f;
    const int wid  = threadIdx.x >> 6;
    const int lane = threadIdx.x & 63;
    const int k    = blockIdx.x * 4 + wid;
    const float4 v = *(const float4*)(emb + (size_t)k * C + lane * 4);
    ushort4 pk = { f2bf(v.x), f2bf(v.y), f2bf(v.z), f2bf(v.w) };
    // c = lane*4 ; ks = c>>5 = lane>>3 ; c&31 = (lane&7)*4
    *(ushort4*)&ebf2[((size_t)(lane >> 3) * K + k) * 32 + (lane & 7) * 4] = pk;
    float s = v.x * v.x + v.y * v.y + v.z * v.z + v.w * v.w;
#pragma unroll
    for (int off = 32; off > 0; off >>= 1) s += __shfl_down(s, off, 64);
    if (lane == 0) esq1[k] = 1.0f + s;
}

// --- kernel 2: distances + argmin only (phases 1-4). 4-wave blocks,
// 64 tokens/block, wave w handles codes [w*256, w*256+256).
// Writes packed argmin index (u16) per token. grid 1024 x 256.
__global__ __launch_bounds__(256, 2) void vq_dist(const float* __restrict__ z,
                                                  const short* __restrict__ ebf2,
                                                  const float* __restrict__ esq1,
                                                  unsigned short* __restrict__ inds) {
    // transpose buffer: [32 ch-blocks][64 tok][8 ch] bf16 = 32 KB
    __shared__ short Zs[32 * 512];
    __shared__ unsigned int warr[4 * 64];   // per-wave packed argmin, per token

    const int tid = threadIdx.x;
    const int wid = tid >> 6;      // wave 0..3
    const int L   = tid & 63;      // lane
    const int q   = L >> 4;        // quad
    const int l15 = L & 15;

    const int bidx = blockIdx.x;
    const int b    = bidx >> 4;           // batch
    const int hw0  = (bidx & 15) * 64;    // position tile base
    const float* zb = z + (size_t)b * C * HW + hw0;

    // ---- phase 1: cooperative transpose, wave w does channels [w*64, w*64+64) ----
#pragma unroll 4
    for (int i = 0; i < 16; ++i) {
        const int c = wid * 64 + i * 4;
        float v0 = zb[(size_t)(c + 0) * HW + L];
        float v1 = zb[(size_t)(c + 1) * HW + L];
        float v2 = zb[(size_t)(c + 2) * HW + L];
        float v3 = zb[(size_t)(c + 3) * HW + L];
        ushort4 pk = { f2bf(v0), f2bf(v1), f2bf(v2), f2bf(v3) };
        *(ushort4*)&Zs[(c >> 3) * 512 + L * 8 + (c & 7)] = pk;
    }
    __syncthreads();

    // ---- phase 2: load B-fragments (all 64 tokens x 256 ch) ----
    bf16x8 zfrag[4][8];
#pragma unroll
    for (int t = 0; t < 4; ++t)
#pragma unroll
        for (int ks = 0; ks < 8; ++ks)
            zfrag[t][ks] = *(const bf16x8*)&Zs[(ks * 4 + q) * 512 + (t * 16 + l15) * 8];

    // ---- phase 3: K loop over this wave's 256-code range, coalesced A loads ----
    unsigned int best[4] = {0xFFFFFFFFu, 0xFFFFFFFFu, 0xFFFFFFFFu, 0xFFFFFFFFu};

    for (int kk = 0; kk < 4; ++kk) {
        const int k0 = wid * 256 + kk * 64;
        floatx4 acc[4][4];   // [m code tile][t token tile]
#pragma unroll
        for (int m = 0; m < 4; ++m)
#pragma unroll
            for (int t = 0; t < 4; ++t) acc[m][t] = (floatx4){0.f, 0.f, 0.f, 0.f};

#pragma unroll
        for (int ks = 0; ks < 8; ++ks) {
            U16 a[4];
#pragma unroll
            for (int m = 0; m < 4; ++m)
                a[m].u = *(const uint4*)(ebf2 + ((size_t)ks * K + (k0 + m * 16 + l15)) * 32 + q * 8);
#pragma unroll
            for (int m = 0; m < 4; ++m)
#pragma unroll
                for (int t = 0; t < 4; ++t)
                    acc[m][t] = __builtin_amdgcn_mfma_f32_16x16x32_bf16(a[m].b, zfrag[t][ks], acc[m][t], 0, 0, 0);
        }

        // distances + packed argmin (d positive: bits monotone; low 10 bits = code)
#pragma unroll
        for (int m = 0; m < 4; ++m) {
            const float4 eq = *(const float4*)&esq1[k0 + m * 16 + q * 4];
            const float eqa[4] = {eq.x, eq.y, eq.z, eq.w};
#pragma unroll
            for (int r = 0; r < 4; ++r) {
                const unsigned int code = (unsigned int)(k0 + m * 16 + q * 4 + r);
#pragma unroll
                for (int t = 0; t < 4; ++t) {
                    float d = fmaf(-2.0f, acc[m][t][r], eqa[r]);
                    unsigned int u = (__float_as_uint(d) & 0xFFFFFC00u) | code;
                    best[t] = best[t] < u ? best[t] : u;
                }
            }
        }
    }

    // ---- phase 4: butterfly argmin across quads, then across waves via LDS ----
#pragma unroll
    for (int t = 0; t < 4; ++t) {
        unsigned int o = (unsigned int)__shfl_xor((int)best[t], 16, 64);
        best[t] = best[t] < o ? best[t] : o;
        o = (unsigned int)__shfl_xor((int)best[t], 32, 64);
        best[t] = best[t] < o ? best[t] : o;
    }
    // lane L owns token L within this wave's code range
    warr[wid * 64 + L] = (q == 0) ? best[0] : (q == 1) ? best[1] : (q == 2) ? best[2] : best[3];
    __syncthreads();

    if (tid < 64) {
        unsigned int u0 = warr[tid];
        unsigned int u1 = warr[64 + tid];
        unsigned int u2 = warr[128 + tid];
        unsigned int u3 = warr[192 + tid];
        u0 = u0 < u1 ? u0 : u1;
        u2 = u2 < u3 ? u2 : u3;
        u0 = u0 < u2 ? u0 : u2;
        inds[bidx * 64 + tid] = (unsigned short)(u0 & 1023u);
    }
}

// --- kernel 3: streaming output + loss. grid 4096 x 256, ~32 regs, full occ.
// block -> token tile (bidx>>2, 64 tokens) x channel quarter (bidx&3, 64 ch).
__global__ __launch_bounds__(256) void vq_out(const float* __restrict__ z,
                                              const float* __restrict__ emb,
                                              const unsigned short* __restrict__ inds,
                                              float* __restrict__ out,
                                              float* __restrict__ acc_loss) {
    __shared__ float lsum[2];
    const int tid = threadIdx.x;
    const int wid = tid >> 6;
    const int L   = tid & 63;

    const int bidx = blockIdx.x >> 2;          // token tile 0..1023
    const int cq   = blockIdx.x & 3;           // channel quarter
    const int b    = bidx >> 4;
    const int hw0  = (bidx & 15) * 64;

    if (tid == 0) { lsum[0] = 0.0f; lsum[1] = 0.0f; }
    __syncthreads();

    const int tok = L;
    const int km  = (int)inds[bidx * 64 + tok];
    const float* erow = emb + (size_t)km * C;

    float s_sq = 0.0f, s_d = 0.0f;
    const size_t base = (size_t)b * C * HW + hw0 + tok;
    const int c0 = cq * 64 + wid * 16;
#pragma unroll
    for (int i = 0; i < 4; ++i) {
        const int c = c0 + i * 4;
        float4 ev = *(const float4*)&erow[c];
        const float eva[4] = {ev.x, ev.y, ev.z, ev.w};
#pragma unroll
        for (int j = 0; j < 4; ++j) {
            float zv = z[base + (size_t)(c + j) * HW];
            float diff = eva[j] - zv;                      // z_q - z
            out[base + (size_t)(c + j) * HW] = zv + diff;  // straight-through fwd
            s_sq = fmaf(diff, diff, s_sq);
            s_d += diff;
        }
    }
#pragma unroll
    for (int off = 32; off > 0; off >>= 1) {
        s_sq += __shfl_down(s_sq, off, 64);
        s_d  += __shfl_down(s_d,  off, 64);
    }
    if (L == 0) {
        atomicAdd(&lsum[0], s_sq);
        atomicAdd(&lsum[1], s_d);
    }
    __syncthreads();
    if (tid == 0) {
        atomicAdd(&acc_loss[0], lsum[0]);
        atomicAdd(&acc_loss[1], lsum[1]);
    }
}

// --- kernel 4: finalize scalar loss ---
__global__ void loss_kernel(const float* __restrict__ acc_loss,
                            float* __restrict__ out_loss) {
    out_loss[0] = acc_loss[0] * NTOT_INV + BETA * (acc_loss[1] * NTOT_INV);
}

extern "C" void kernel_launch(void* const* d_in, const int* in_sizes, int n_in,
                              void* d_out, int out_size, void* d_ws, size_t ws_size,
                              hipStream_t stream) {
    const float* z   = (const float*)d_in[0];   // [64,256,32,32]
    const float* emb = (const float*)d_in[1];   // [1024,256]
    float* out = (float*)d_out;                 // [16777216 z_q] + [1 loss]
    float* ws  = (float*)d_ws;
    float* acc  = ws;                               // 2 floats
    float* esq1 = ws + 64;                          // 1024 floats
    short* ebf2 = (short*)(ws + 64 + 1024);         // 1024*256 bf16 = 512 KB (tiled)
    unsigned short* inds = (unsigned short*)(ebf2 + (size_t)K * C);  // 65536 u16 = 128 KB

    prep_kernel<<<dim3(K / 4), 256, 0, stream>>>(emb, ebf2, esq1, acc);
    vq_dist<<<dim3(1024), 256, 0, stream>>>(z, ebf2, esq1, inds);
    vq_out<<<dim3(4096), 256, 0, stream>>>(z, emb, inds, out, acc);
    loss_kernel<<<1, 1, 0, stream>>>(acc, out + (size_t)B * C * HW);
}

// Round 4
// 234.174 us; speedup vs baseline: 1.0868x; 1.0868x over previous
//
#include <hip/hip_runtime.h>
#include <hip/hip_bf16.h>
#include <float.h>

// Problem constants
constexpr int B  = 64;
constexpr int C  = 256;
constexpr int HW = 1024;   // 32*32
constexpr int K  = 1024;
constexpr int NTOK = B * HW;   // 65536
constexpr float BETA = 0.25f;
constexpr float NTOT_INV = 1.0f / 16777216.0f;  // 1 / (64*256*32*32)

typedef __attribute__((ext_vector_type(8))) short bf16x8;
typedef __attribute__((ext_vector_type(4))) float floatx4;

union U16 { uint4 u; bf16x8 b; };

__device__ inline unsigned short f2bf(float x) {
    unsigned u = __float_as_uint(x);
    return (unsigned short)((u + 0x7FFFu + ((u >> 16) & 1u)) >> 16);  // RNE
}

// --- kernel 1: emb fp32 -> bf16 TILED [ks=ch/32][code][ch%32] + esq1 ---
// grid 256 x 256 threads. Also zeroes loss accumulators.
__global__ __launch_bounds__(256) void prep_kernel(const float* __restrict__ emb,
                                                   short* __restrict__ ebf2,
                                                   float* __restrict__ esq1,
                                                   float* __restrict__ acc_loss) {
    if (blockIdx.x == 0 && threadIdx.x < 2) acc_loss[threadIdx.x] = 0.0f;
    const int wid  = threadIdx.x >> 6;
    const int lane = threadIdx.x & 63;
    const int k    = blockIdx.x * 4 + wid;
    const float4 v = *(const float4*)(emb + (size_t)k * C + lane * 4);
    ushort4 pk = { f2bf(v.x), f2bf(v.y), f2bf(v.z), f2bf(v.w) };
    // c = lane*4 ; ks = lane>>3 ; c&31 = (lane&7)*4
    *(ushort4*)&ebf2[((size_t)(lane >> 3) * K + k) * 32 + (lane & 7) * 4] = pk;
    float s = v.x * v.x + v.y * v.y + v.z * v.z + v.w * v.w;
#pragma unroll
    for (int off = 32; off > 0; off >>= 1) s += __shfl_down(s, off, 64);
    if (lane == 0) esq1[k] = 1.0f + s;
}

// --- kernel 2: z NCHW f32 -> zt2[ks=8][tok=65536][32ch] bf16 (token-major tiled).
// All global accesses are 1KB-contiguous wave bursts (16B/lane); the NCHW->token
// transpose goes through LDS. grid 256 blocks (b, hw-quarter) x 512 threads.
__global__ __launch_bounds__(512) void zt_kernel(const float* __restrict__ z,
                                                 short* __restrict__ zt2) {
    // U[tok_local=256][33 uints]; uint packs bf16 channel pair (c, c+1). +1 pad.
    __shared__ unsigned int U[256 * 33];   // 33 KB
    const int tid = threadIdx.x;           // 0..511
    const int wv  = tid >> 6;              // wave 0..7
    const int L   = tid & 63;
    const int b   = blockIdx.x >> 2;
    const int hw0 = (blockIdx.x & 3) * 256;
    const float* zb = z + (size_t)b * C * HW;

    for (int ch0 = 0; ch0 < C; ch0 += 64) {
        // stage-in: wave wv reads channels ch0+wv*8 .. +7, each as one 1KB burst
        float4 va[8];
#pragma unroll
        for (int i = 0; i < 8; ++i) {
            const int c = ch0 + wv * 8 + i;
            va[i] = *(const float4*)(zb + (size_t)c * HW + hw0 + L * 4);
        }
#pragma unroll
        for (int i = 0; i < 8; i += 2) {
            const int cu = (wv * 8 + i) >> 1;          // uint column in chunk
            const float* p0 = (const float*)&va[i];
            const float* p1 = (const float*)&va[i + 1];
#pragma unroll
            for (int j = 0; j < 4; ++j) {
                unsigned int u = ((unsigned int)f2bf(p0[j])) |
                                 ((unsigned int)f2bf(p1[j]) << 16);
                U[(L * 4 + j) * 33 + cu] = u;
            }
        }
        __syncthreads();
        // stage-out: 2 ks slices, 32KB total, 1KB-contiguous wave bursts
#pragma unroll
        for (int r = 0; r < 4; ++r) {
            const int slot  = r * 512 + tid;      // 0..2047 x 16B
            const int ksl   = slot >> 10;         // 0..1
            const int rem   = slot & 1023;
            const int tokl  = rem >> 2;
            const int piece = rem & 3;
            const int cb = ksl * 16 + piece * 4;
            uint4 w;
            w.x = U[tokl * 33 + cb + 0];
            w.y = U[tokl * 33 + cb + 1];
            w.z = U[tokl * 33 + cb + 2];
            w.w = U[tokl * 33 + cb + 3];
            const int ks = (ch0 >> 5) + ksl;
            const size_t tok = (size_t)b * HW + hw0 + tokl;
            *(uint4*)((unsigned short*)zt2 + ((size_t)ks * NTOK + tok) * 32 + piece * 8) = w;
        }
        __syncthreads();
    }
}

// --- kernel 3: distances + argmin. 4 waves/block, 64 tokens/block,
// wave w handles codes [w*256, w*256+256). zfrag straight from zt2 (coalesced).
// launch_bounds(256,1): body needs ~190 regs; grid gives 4 waves/SIMD anyway.
__global__ __launch_bounds__(256, 1) void vq_dist(const short* __restrict__ zt2,
                                                  const short* __restrict__ ebf2,
                                                  const float* __restrict__ esq1,
                                                  unsigned short* __restrict__ inds) {
    __shared__ unsigned int warr[4 * 64];

    const int tid = threadIdx.x;
    const int wid = tid >> 6;
    const int L   = tid & 63;
    const int q   = L >> 4;
    const int l15 = L & 15;
    const int tok0 = blockIdx.x * 64;

    // zfrag[t][ks]: token = tok0 + t*16 + l15, ch = ks*32 + q*8 + j  (1KB bursts)
    bf16x8 zfrag[4][8];
#pragma unroll
    for (int t = 0; t < 4; ++t)
#pragma unroll
        for (int ks = 0; ks < 8; ++ks)
            zfrag[t][ks] = *(const bf16x8*)(zt2 +
                ((size_t)ks * NTOK + tok0 + t * 16 + l15) * 32 + q * 8);

    unsigned int best[4] = {0xFFFFFFFFu, 0xFFFFFFFFu, 0xFFFFFFFFu, 0xFFFFFFFFu};

    for (int kk = 0; kk < 4; ++kk) {
        const int k0 = wid * 256 + kk * 64;
        floatx4 acc[4][4];   // [m code tile][t token tile]
#pragma unroll
        for (int m = 0; m < 4; ++m)
#pragma unroll
            for (int t = 0; t < 4; ++t) acc[m][t] = (floatx4){0.f, 0.f, 0.f, 0.f};

#pragma unroll
        for (int ks = 0; ks < 8; ++ks) {
            U16 a[4];
#pragma unroll
            for (int m = 0; m < 4; ++m)
                a[m].u = *(const uint4*)(ebf2 + ((size_t)ks * K + (k0 + m * 16 + l15)) * 32 + q * 8);
#pragma unroll
            for (int m = 0; m < 4; ++m)
#pragma unroll
                for (int t = 0; t < 4; ++t)
                    acc[m][t] = __builtin_amdgcn_mfma_f32_16x16x32_bf16(a[m].b, zfrag[t][ks], acc[m][t], 0, 0, 0);
        }

        // distances + packed argmin (d positive: bits monotone; low 10 bits = code)
#pragma unroll
        for (int m = 0; m < 4; ++m) {
            const float4 eq = *(const float4*)&esq1[k0 + m * 16 + q * 4];
            const float eqa[4] = {eq.x, eq.y, eq.z, eq.w};
#pragma unroll
            for (int r = 0; r < 4; ++r) {
                const unsigned int code = (unsigned int)(k0 + m * 16 + q * 4 + r);
#pragma unroll
                for (int t = 0; t < 4; ++t) {
                    float d = fmaf(-2.0f, acc[m][t][r], eqa[r]);
                    unsigned int u = (__float_as_uint(d) & 0xFFFFFC00u) | code;
                    best[t] = best[t] < u ? best[t] : u;
                }
            }
        }
    }

    // butterfly argmin across quads, then across waves via LDS
#pragma unroll
    for (int t = 0; t < 4; ++t) {
        unsigned int o = (unsigned int)__shfl_xor((int)best[t], 16, 64);
        best[t] = best[t] < o ? best[t] : o;
        o = (unsigned int)__shfl_xor((int)best[t], 32, 64);
        best[t] = best[t] < o ? best[t] : o;
    }
    warr[wid * 64 + L] = (q == 0) ? best[0] : (q == 1) ? best[1] : (q == 2) ? best[2] : best[3];
    __syncthreads();

    if (tid < 64) {
        unsigned int u0 = warr[tid];
        unsigned int u1 = warr[64 + tid];
        unsigned int u2 = warr[128 + tid];
        unsigned int u3 = warr[192 + tid];
        u0 = u0 < u1 ? u0 : u1;
        u2 = u2 < u3 ? u2 : u3;
        u0 = u0 < u2 ? u0 : u2;
        inds[tok0 + tid] = (unsigned short)(u0 & 1023u);
    }
}

// --- kernel 4: streaming output + loss, native hw-major direction.
// grid 2048 (b x ch-octet) x 256 threads. Wave wv owns channels c0+2wv, c0+2wv+1
// over all 1024 hw. z reads / out writes are 1KB-contiguous wave bursts.
__global__ __launch_bounds__(256) void vq_out(const float* __restrict__ z,
                                              const float* __restrict__ emb,
                                              const unsigned short* __restrict__ inds,
                                              float* __restrict__ out,
                                              float* __restrict__ acc_loss) {
    __shared__ float lsum[2];
    const int tid = threadIdx.x;
    const int wv  = tid >> 6;
    const int L   = tid & 63;
    const int b   = blockIdx.x >> 5;
    const int c0  = (blockIdx.x & 31) * 8;

    if (tid == 0) { lsum[0] = 0.0f; lsum[1] = 0.0f; }
    __syncthreads();

    const int ca = c0 + wv * 2;                               // even
    const float* za  = z   + ((size_t)b * C + ca) * HW;
    const float* zb2 = za + HW;
    float* oa = out + ((size_t)b * C + ca) * HW;
    float* ob = oa + HW;
    const unsigned short* ib = inds + b * HW;

    float s_sq = 0.0f, s_d = 0.0f;
#pragma unroll
    for (int hc = 0; hc < 4; ++hc) {
        const int hw = hc * 256 + L * 4;
        ushort4 kmv = *(const ushort4*)(ib + hw);
        float4 z0 = *(const float4*)(za + hw);
        float4 z1 = *(const float4*)(zb2 + hw);
        const unsigned short kma[4] = {kmv.x, kmv.y, kmv.z, kmv.w};
        float e0[4], e1[4];
#pragma unroll
        for (int j = 0; j < 4; ++j) {
            float2 ev = *(const float2*)(emb + (size_t)kma[j] * C + ca);
            e0[j] = ev.x; e1[j] = ev.y;
        }
        const float z0a[4] = {z0.x, z0.y, z0.z, z0.w};
        const float z1a[4] = {z1.x, z1.y, z1.z, z1.w};
        float o0a[4], o1a[4];
#pragma unroll
        for (int j = 0; j < 4; ++j) {
            float d0 = e0[j] - z0a[j];
            float d1 = e1[j] - z1a[j];
            o0a[j] = z0a[j] + d0;            // straight-through fwd
            o1a[j] = z1a[j] + d1;
            s_sq = fmaf(d0, d0, s_sq);
            s_sq = fmaf(d1, d1, s_sq);
            s_d += d0 + d1;
        }
        *(float4*)(oa + hw) = (float4){o0a[0], o0a[1], o0a[2], o0a[3]};
        *(float4*)(ob + hw) = (float4){o1a[0], o1a[1], o1a[2], o1a[3]};
    }
#pragma unroll
    for (int off = 32; off > 0; off >>= 1) {
        s_sq += __shfl_down(s_sq, off, 64);
        s_d  += __shfl_down(s_d,  off, 64);
    }
    if (L == 0) {
        atomicAdd(&lsum[0], s_sq);
        atomicAdd(&lsum[1], s_d);
    }
    __syncthreads();
    if (tid == 0) {
        atomicAdd(&acc_loss[0], lsum[0]);
        atomicAdd(&acc_loss[1], lsum[1]);
    }
}

// --- kernel 5: finalize scalar loss ---
__global__ void loss_kernel(const float* __restrict__ acc_loss,
                            float* __restrict__ out_loss) {
    out_loss[0] = acc_loss[0] * NTOT_INV + BETA * (acc_loss[1] * NTOT_INV);
}

extern "C" void kernel_launch(void* const* d_in, const int* in_sizes, int n_in,
                              void* d_out, int out_size, void* d_ws, size_t ws_size,
                              hipStream_t stream) {
    const float* z   = (const float*)d_in[0];   // [64,256,32,32]
    const float* emb = (const float*)d_in[1];   // [1024,256]
    float* out = (float*)d_out;                 // [16777216 z_q] + [1 loss]
    float* ws  = (float*)d_ws;
    float* acc  = ws;                               // 2 floats
    float* esq1 = ws + 64;                          // 1024 floats
    short* ebf2 = (short*)(ws + 64 + 1024);         // 512 KB (tiled codebook)
    unsigned short* inds = (unsigned short*)(ebf2 + (size_t)K * C);  // 128 KB
    // zt2 (32 MB) lives in the out buffer as scratch; it is fully consumed by
    // vq_dist before vq_out overwrites out (same-stream ordering).
    short* zt2 = (short*)out;

    prep_kernel<<<dim3(K / 4), 256, 0, stream>>>(emb, ebf2, esq1, acc);
    zt_kernel<<<dim3(256), 512, 0, stream>>>(z, zt2);
    vq_dist<<<dim3(1024), 256, 0, stream>>>(zt2, ebf2, esq1, inds);
    vq_out<<<dim3(2048), 256, 0, stream>>>(z, emb, inds, out, acc);
    loss_kernel<<<1, 1, 0, stream>>>(acc, out + (size_t)B * C * HW);
}